// Round 9
// baseline (121.344 us; speedup 1.0000x reference)
//
#include <hip/hip_runtime.h>

#define D 128
#define KK 256  // concatenated K (feat | ah)

typedef __attribute__((ext_vector_type(8))) short short8;
typedef __attribute__((ext_vector_type(4))) float f32x4;
typedef __attribute__((ext_vector_type(2))) float f32x2;

__device__ __forceinline__ ushort f2bf(float x) {  // RNE f32 -> bf16 bits
  union { float f; uint u; } v; v.f = x;
  uint r = v.u + 0x7fffu + ((v.u >> 16) & 1u);
  return (ushort)(r >> 16);
}

// ---------------------------------------------------------------------------
// Fused: feat f32 -> fp8(e4m3) convert (16 floats/thread, tid<total16)
//      + W convert (tid < D*D)
//      + per-dst 8-way STRIPED histogram (tid<E, fire-and-forget atomics)
//      + scan phase 1 (blocks < nb: intra-block excl scan of (int)in_norm)
// ---------------------------------------------------------------------------
__global__ __launch_bounds__(256) void conv_all(
    const float* __restrict__ feat, uint* __restrict__ featf8, int total16,
    const float* __restrict__ w1, const float* __restrict__ w2,
    ushort* __restrict__ W,
    const float* __restrict__ in_norm, int* __restrict__ offs,
    int* __restrict__ bsums, int n,
    const int* __restrict__ dst, uint* __restrict__ cnt8, int E) {
  int tid = blockIdx.x * 256 + threadIdx.x;
  if (tid < total16) {
    uint f8[4];
#pragma unroll
    for (int t = 0; t < 4; ++t) {
      float4 f = ((const float4*)feat)[tid * 4 + t];
      uint r = __builtin_amdgcn_cvt_pk_fp8_f32(f.x, f.y, 0, false);
      r = (uint)__builtin_amdgcn_cvt_pk_fp8_f32(f.z, f.w, (int)r, true);
      f8[t] = r;
    }
    ((uint4*)featf8)[tid] = make_uint4(f8[0], f8[1], f8[2], f8[3]);
  }
  if (tid < D * D) {
    int o = tid >> 7, k = tid & (D - 1);
    W[o * KK + k]     = f2bf(w1[tid]);
    W[o * KK + D + k] = f2bf(w2[tid]);
  }
  if (tid < E) {  // no-return atomic, striped -> low per-line contention
    int v = dst[tid];
    atomicAdd(&cnt8[(size_t)(tid & 7) * n + v], 1u);
  }
  int nb = (n + 255) >> 8;
  if ((int)blockIdx.x < nb) {
    __shared__ int tmp[256];
    int t = threadIdx.x;
    int i = blockIdx.x * 256 + t;
    int v = (i < n) ? (int)in_norm[i] : 0;
    tmp[t] = v;
    __syncthreads();
    for (int off = 1; off < 256; off <<= 1) {
      int a = tmp[t];
      int b = (t >= off) ? tmp[t - off] : 0;
      __syncthreads();
      tmp[t] = a + b;
      __syncthreads();
    }
    if (i < n) offs[i] = tmp[t] - v;  // intra-block exclusive
    if (t == 255) bsums[blockIdx.x] = tmp[255];
  }
}

// ---------------------------------------------------------------------------
// Per-dst bases. Every block first redundantly scans the (<=256) raw block
// sums in LDS, then per v: finalize offs, exclusive-prefix the 8 striped
// sub-counts -> cursor8 bases, endo = true segment end.
// ---------------------------------------------------------------------------
__global__ __launch_bounds__(256) void bases_kernel(
    int* __restrict__ offs, const int* __restrict__ bsums,
    const uint* __restrict__ cnt8, uint* __restrict__ cursor8,
    int* __restrict__ endo, int n, int nb) {
  __shared__ int tmp[256];
  int t = threadIdx.x;
  int bv = (t < nb) ? bsums[t] : 0;
  tmp[t] = bv;
  __syncthreads();
  for (int off = 1; off < 256; off <<= 1) {
    int a = tmp[t];
    int b = (t >= off) ? tmp[t - off] : 0;
    __syncthreads();
    tmp[t] = a + b;
    __syncthreads();
  }
  int v = blockIdx.x * 256 + t;
  if (v >= n) return;
  int blk = v >> 8;
  uint off0 = (uint)(offs[v] + tmp[blk] - bsums[blk]);
  offs[v] = (int)off0;
  uint p = off0;
  uint base[8];
#pragma unroll
  for (int j = 0; j < 8; ++j) {
    base[j] = p;
    p += cnt8[(size_t)j * n + v];
  }
#pragma unroll
  for (int j = 0; j < 8; ++j) cursor8[(size_t)j * n + v] = base[j];
  endo[v] = (int)p;
}

// striped 8-way privatized scatter; csr payload is int32 (aligned 4B random
// stores -> no sub-dword ECC RMW path)
__global__ __launch_bounds__(256) void scatter8(
    const int* __restrict__ src, const int* __restrict__ dst,
    uint* __restrict__ cursor8, int* __restrict__ csr, int E, int n) {
  int e = blockIdx.x * 256 + threadIdx.x;
  if (e < E) {
    int v = dst[e];
    uint p = atomicAdd(&cursor8[(size_t)(e & 7) * n + v], 1u);
    csr[p] = src[e];
  }
}

// ---------------------------------------------------------------------------
// dst-major gather from fp8 feat; one wave per row, 2 edges per iteration
// (half-wave per edge, 1 dword = 4 fp8 per lane), f32 accumulation,
// halves combined via shfl_xor(32), /in_norm folded in, ah written bf16.
// ---------------------------------------------------------------------------
__global__ __launch_bounds__(256) void gather_rows(
    const uint* __restrict__ featf8, const int* __restrict__ csr,
    const int* __restrict__ offs, const int* __restrict__ endo,
    const float* __restrict__ in_norm, ushort* __restrict__ ahb, int ndst) {
  int row = blockIdx.x * 4 + (threadIdx.x >> 6);
  if (row >= ndst) return;
  int lane = threadIdx.x & 63;
  int half = lane >> 5;
  int l32 = lane & 31;
  int beg = offs[row];
  int end = endo[row];
  float4 a0 = make_float4(0.f, 0.f, 0.f, 0.f);
  float4 a1 = a0;
  int j = beg;
  for (; j + 7 < end; j += 8) {  // 8 edges per iter, 4 loads/lane in flight
    uint p[4];
#pragma unroll
    for (int t = 0; t < 4; ++t) {
      int u = csr[j + 2 * t + half];
      p[t] = featf8[u * 32 + l32];
    }
#pragma unroll
    for (int t = 0; t < 4; ++t) {
      f32x2 lo = __builtin_amdgcn_cvt_pk_f32_fp8((int)p[t], false);
      f32x2 hi = __builtin_amdgcn_cvt_pk_f32_fp8((int)p[t], true);
      if (t & 1) {
        a1.x += lo[0]; a1.y += lo[1]; a1.z += hi[0]; a1.w += hi[1];
      } else {
        a0.x += lo[0]; a0.y += lo[1]; a0.z += hi[0]; a0.w += hi[1];
      }
    }
  }
  for (; j + 1 < end; j += 2) {
    int u = csr[j + half];
    uint p = featf8[u * 32 + l32];
    f32x2 lo = __builtin_amdgcn_cvt_pk_f32_fp8((int)p, false);
    f32x2 hi = __builtin_amdgcn_cvt_pk_f32_fp8((int)p, true);
    a0.x += lo[0]; a0.y += lo[1]; a0.z += hi[0]; a0.w += hi[1];
  }
  if (j < end && half == 0) {  // odd tail: half 0 only
    uint p = featf8[(int)csr[j] * 32 + l32];
    f32x2 lo = __builtin_amdgcn_cvt_pk_f32_fp8((int)p, false);
    f32x2 hi = __builtin_amdgcn_cvt_pk_f32_fp8((int)p, true);
    a1.x += lo[0]; a1.y += lo[1]; a1.z += hi[0]; a1.w += hi[1];
  }
  float sx = a0.x + a1.x, sy = a0.y + a1.y;
  float sz = a0.z + a1.z, sw = a0.w + a1.w;
  sx += __shfl_xor(sx, 32);
  sy += __shfl_xor(sy, 32);
  sz += __shfl_xor(sz, 32);
  sw += __shfl_xor(sw, 32);
  if (half == 0) {
    float inv = 1.0f / in_norm[row];
    ushort4 o;
    o.x = f2bf(sx * inv); o.y = f2bf(sy * inv);
    o.z = f2bf(sz * inv); o.w = f2bf(sw * inv);
    ((ushort4*)(ahb + (size_t)row * D))[l32] = o;
  }
}

// ---------------------------------------------------------------------------
// MFMA GEMM: out[m][o] = sum_k feat[m][k]*W[o][k] (k<128, f32 read + RNE)
//                      + sum_k ahb[m][k]*W[o][128+k] + b1[o]+b2[o]
// Block = 4 waves = 64 rows; wave = 16 rows x 128 cols; K=256 in 8 steps.
// ---------------------------------------------------------------------------
__global__ __launch_bounds__(256) void gemm_mfma(
    const float* __restrict__ feat, const ushort* __restrict__ ahb,
    const ushort* __restrict__ W, const float* __restrict__ b1,
    const float* __restrict__ b2, float* __restrict__ out, int ndst) {
  int wid = threadIdx.x >> 6;
  int lane = threadIdx.x & 63;
  int row0 = blockIdx.x * 64 + wid * 16;
  int r = lane & 15;
  int kg = lane >> 4;
  int arow = row0 + r;
  if (arow >= ndst) arow = ndst - 1;  // clamped lanes' results are discarded

  short8 afrag[8];
  const float* fr = feat + (size_t)arow * D;
  const ushort* ar = ahb + (size_t)arow * D;
#pragma unroll
  for (int s = 0; s < 4; ++s) {
    float4 lo = *(const float4*)(fr + s * 32 + kg * 8);
    float4 hi = *(const float4*)(fr + s * 32 + kg * 8 + 4);
    short8 t;
    t[0] = (short)f2bf(lo.x); t[1] = (short)f2bf(lo.y);
    t[2] = (short)f2bf(lo.z); t[3] = (short)f2bf(lo.w);
    t[4] = (short)f2bf(hi.x); t[5] = (short)f2bf(hi.y);
    t[6] = (short)f2bf(hi.z); t[7] = (short)f2bf(hi.w);
    afrag[s] = t;
    afrag[4 + s] = *(const short8*)(ar + s * 32 + kg * 8);
  }

  f32x4 acc[8];
#pragma unroll
  for (int n = 0; n < 8; ++n) acc[n] = (f32x4){0.f, 0.f, 0.f, 0.f};

#pragma unroll
  for (int n = 0; n < 8; ++n) {
    const ushort* wr = W + (size_t)(n * 16 + r) * KK;
#pragma unroll
    for (int s = 0; s < 8; ++s) {
      short8 bfrag = *(const short8*)(wr + s * 32 + kg * 8);
      acc[n] = __builtin_amdgcn_mfma_f32_16x16x32_bf16(afrag[s], bfrag, acc[n], 0, 0, 0);
    }
  }

#pragma unroll
  for (int n = 0; n < 8; ++n) {
    int col = n * 16 + r;
    float bb = b1[col] + b2[col];
#pragma unroll
    for (int q = 0; q < 4; ++q) {
      int orow = row0 + kg * 4 + q;
      if (orow < ndst) out[(size_t)orow * D + col] = acc[n][q] + bb;
    }
  }
}

extern "C" void kernel_launch(void* const* d_in, const int* in_sizes, int n_in,
                              void* d_out, int out_size, void* d_ws, size_t ws_size,
                              hipStream_t stream) {
  const float* feat    = (const float*)d_in[0];
  const float* in_norm = (const float*)d_in[1];
  const float* w1      = (const float*)d_in[2];
  const float* b1      = (const float*)d_in[3];
  const float* w2      = (const float*)d_in[4];
  const float* b2      = (const float*)d_in[5];
  const int*   src     = (const int*)d_in[6];
  const int*   dst     = (const int*)d_in[7];
  float*       out     = (float*)d_out;

  int E    = in_sizes[6];
  int ndst = in_sizes[1];
  int featn = in_sizes[0];  // N_SRC * D

  // workspace layout (16B-aligned pieces)
  char* ws = (char*)d_ws;
  uint* featf8 = (uint*)ws;                                    // featn fp8
  size_t off = (size_t)featn;
  ushort* ahb = (ushort*)(ws + off);  off += (size_t)ndst * D * sizeof(ushort);
  ushort* W = (ushort*)(ws + off);    off += (size_t)D * KK * sizeof(ushort);
  int* csr = (int*)(ws + off);        off += (size_t)E * sizeof(int);
  int* offs = (int*)(ws + off);       off += (size_t)ndst * sizeof(int);
  int* endo = (int*)(ws + off);       off += (size_t)ndst * sizeof(int);
  uint* cnt8 = (uint*)(ws + off);     off += (size_t)ndst * 8 * sizeof(uint);
  uint* cursor8 = (uint*)(ws + off);  off += (size_t)ndst * 8 * sizeof(uint);
  int* bsums = (int*)(ws + off);

  int total16 = featn / 16;                    // 16 floats per thread
  int nb = (ndst + 255) / 256;                 // scan blocks (98 <= 256)
  int cblocks = (E + 255) / 256;               // covers hist (E) > convert
  if (cblocks < (total16 + 255) / 256) cblocks = (total16 + 255) / 256;
  if (cblocks < nb) cblocks = nb;

  hipMemsetAsync(cnt8, 0, (size_t)ndst * 8 * sizeof(uint), stream);

  conv_all<<<cblocks, 256, 0, stream>>>(
      feat, featf8, total16, w1, w2, W, in_norm, offs, bsums, ndst,
      dst, cnt8, E);
  bases_kernel<<<nb, 256, 0, stream>>>(offs, bsums, cnt8, cursor8, endo, ndst, nb);
  scatter8<<<(E + 255) / 256, 256, 0, stream>>>(src, dst, cursor8, csr, E, ndst);
  gather_rows<<<(ndst + 3) / 4, 256, 0, stream>>>(
      featf8, csr, offs, endo, in_norm, ahb, ndst);
  gemm_mfma<<<(ndst + 63) / 64, 256, 0, stream>>>(
      feat, ahb, W, b1, b2, out, ndst);
}

// Round 10
// 90.937 us; speedup vs baseline: 1.3344x; 1.3344x over previous
//
#include <hip/hip_runtime.h>

#define D 128
#define KK 256   // concatenated K (feat | ah)
#define CH 2048  // edges per scatter chunk

typedef __attribute__((ext_vector_type(8))) short short8;
typedef __attribute__((ext_vector_type(4))) float f32x4;
typedef __attribute__((ext_vector_type(2))) float f32x2;

__device__ __forceinline__ ushort f2bf(float x) {  // RNE f32 -> bf16 bits
  union { float f; uint u; } v; v.f = x;
  uint r = v.u + 0x7fffu + ((v.u >> 16) & 1u);
  return (ushort)(r >> 16);
}

// ---------------------------------------------------------------------------
// Fused: feat f32 -> fp8(e4m3) convert (16 floats/thread, tid<total16)
//      + W convert (tid < D*D)
//      + scan phase 1 (blocks < nb: intra-block excl scan of (int)in_norm)
// ---------------------------------------------------------------------------
__global__ __launch_bounds__(256) void conv_all(
    const float* __restrict__ feat, uint* __restrict__ featf8, int total16,
    const float* __restrict__ w1, const float* __restrict__ w2,
    ushort* __restrict__ W,
    const float* __restrict__ in_norm, int* __restrict__ offs,
    int* __restrict__ bsums, int n) {
  int tid = blockIdx.x * 256 + threadIdx.x;
  if (tid < total16) {
    uint f8[4];
#pragma unroll
    for (int t = 0; t < 4; ++t) {
      float4 f = ((const float4*)feat)[tid * 4 + t];
      uint r = __builtin_amdgcn_cvt_pk_fp8_f32(f.x, f.y, 0, false);
      r = (uint)__builtin_amdgcn_cvt_pk_fp8_f32(f.z, f.w, (int)r, true);
      f8[t] = r;
    }
    ((uint4*)featf8)[tid] = make_uint4(f8[0], f8[1], f8[2], f8[3]);
  }
  if (tid < D * D) {
    int o = tid >> 7, k = tid & (D - 1);
    W[o * KK + k]     = f2bf(w1[tid]);
    W[o * KK + D + k] = f2bf(w2[tid]);
  }
  int nb = (n + 255) >> 8;
  if ((int)blockIdx.x < nb) {
    __shared__ int tmp[256];
    int t = threadIdx.x;
    int i = blockIdx.x * 256 + t;
    int v = (i < n) ? (int)in_norm[i] : 0;
    tmp[t] = v;
    __syncthreads();
    for (int off = 1; off < 256; off <<= 1) {
      int a = tmp[t];
      int b = (t >= off) ? tmp[t - off] : 0;
      __syncthreads();
      tmp[t] = a + b;
      __syncthreads();
    }
    if (i < n) offs[i] = tmp[t] - v;  // intra-block exclusive
    if (t == 255) bsums[blockIdx.x] = tmp[255];
  }
}

// ---------------------------------------------------------------------------
// Finalize: every block redundantly LDS-scans the (<=256) raw block sums,
// then offs[v] += block base; cursor[v] = offs[v].
// ---------------------------------------------------------------------------
__global__ __launch_bounds__(256) void finalize_offs(
    int* __restrict__ offs, const int* __restrict__ bsums,
    int* __restrict__ cursor, int n, int nb) {
  __shared__ int tmp[256];
  int t = threadIdx.x;
  tmp[t] = (t < nb) ? bsums[t] : 0;
  __syncthreads();
  for (int off = 1; off < 256; off <<= 1) {
    int a = tmp[t];
    int b = (t >= off) ? tmp[t - off] : 0;
    __syncthreads();
    tmp[t] = a + b;
    __syncthreads();
  }
  int v = blockIdx.x * 256 + t;
  if (v >= n) return;
  int blk = v >> 8;
  int o = offs[v] + tmp[blk] - bsums[blk];  // + exclusive block base
  offs[v] = o;
  cursor[v] = o;
}

// ---------------------------------------------------------------------------
// XCD-range-partitioned scatter: r = blockIdx&7 (bid%8 ~ XCD round-robin).
// Blocks with equal r sweep all edges, handling only dst in range r.
// csr lines for a given range are written by ONE XCD -> lines fill in that
// XCD's L2 before eviction (no cross-XCD partial-line merge traffic).
// ---------------------------------------------------------------------------
__global__ __launch_bounds__(256) void scatterx(
    const int* __restrict__ src, const int* __restrict__ dst,
    int* __restrict__ cursor, ushort* __restrict__ csr, int E, int n) {
  int r = blockIdx.x & 7;
  int j = blockIdx.x >> 3;
  int e0 = j * CH;
  int e1 = min(e0 + CH, E);
  int lo = (r * n) >> 3;
  int hi = ((r + 1) * n) >> 3;
  for (int e = e0 + threadIdx.x; e < e1; e += 256) {
    int v = dst[e];
    if (v >= lo && v < hi) {
      int p = atomicAdd(&cursor[v], 1);
      csr[p] = (ushort)src[e];
    }
  }
}

// ---------------------------------------------------------------------------
// dst-major gather from fp8 feat; one wave per row, 2 edges per iteration
// (half-wave per edge, 1 dword = 4 fp8 per lane), f32 accumulation,
// halves combined via shfl_xor(32), /in_norm folded in, ah written bf16.
// end = cursor[row] (post-scatter = offs + true degree).
// ---------------------------------------------------------------------------
__global__ __launch_bounds__(256) void gather_rows(
    const uint* __restrict__ featf8, const ushort* __restrict__ csr,
    const int* __restrict__ offs, const int* __restrict__ cursor,
    const float* __restrict__ in_norm, ushort* __restrict__ ahb, int ndst) {
  int row = blockIdx.x * 4 + (threadIdx.x >> 6);
  if (row >= ndst) return;
  int lane = threadIdx.x & 63;
  int half = lane >> 5;
  int l32 = lane & 31;
  int beg = offs[row];
  int end = cursor[row];
  float4 a0 = make_float4(0.f, 0.f, 0.f, 0.f);
  float4 a1 = a0;
  int j = beg;
  for (; j + 7 < end; j += 8) {  // 8 edges per iter, 4 loads/lane in flight
    uint p[4];
#pragma unroll
    for (int t = 0; t < 4; ++t) {
      int u = csr[j + 2 * t + half];
      p[t] = featf8[u * 32 + l32];
    }
#pragma unroll
    for (int t = 0; t < 4; ++t) {
      f32x2 lo = __builtin_amdgcn_cvt_pk_f32_fp8((int)p[t], false);
      f32x2 hi = __builtin_amdgcn_cvt_pk_f32_fp8((int)p[t], true);
      if (t & 1) {
        a1.x += lo[0]; a1.y += lo[1]; a1.z += hi[0]; a1.w += hi[1];
      } else {
        a0.x += lo[0]; a0.y += lo[1]; a0.z += hi[0]; a0.w += hi[1];
      }
    }
  }
  for (; j + 1 < end; j += 2) {
    int u = csr[j + half];
    uint p = featf8[u * 32 + l32];
    f32x2 lo = __builtin_amdgcn_cvt_pk_f32_fp8((int)p, false);
    f32x2 hi = __builtin_amdgcn_cvt_pk_f32_fp8((int)p, true);
    a0.x += lo[0]; a0.y += lo[1]; a0.z += hi[0]; a0.w += hi[1];
  }
  if (j < end && half == 0) {  // odd tail: half 0 only
    uint p = featf8[(int)csr[j] * 32 + l32];
    f32x2 lo = __builtin_amdgcn_cvt_pk_f32_fp8((int)p, false);
    f32x2 hi = __builtin_amdgcn_cvt_pk_f32_fp8((int)p, true);
    a1.x += lo[0]; a1.y += lo[1]; a1.z += hi[0]; a1.w += hi[1];
  }
  float sx = a0.x + a1.x, sy = a0.y + a1.y;
  float sz = a0.z + a1.z, sw = a0.w + a1.w;
  sx += __shfl_xor(sx, 32);
  sy += __shfl_xor(sy, 32);
  sz += __shfl_xor(sz, 32);
  sw += __shfl_xor(sw, 32);
  if (half == 0) {
    float inv = 1.0f / in_norm[row];
    ushort4 o;
    o.x = f2bf(sx * inv); o.y = f2bf(sy * inv);
    o.z = f2bf(sz * inv); o.w = f2bf(sw * inv);
    ((ushort4*)(ahb + (size_t)row * D))[l32] = o;
  }
}

// ---------------------------------------------------------------------------
// MFMA GEMM: out[m][o] = sum_k feat[m][k]*W[o][k] (k<128, f32 read + RNE)
//                      + sum_k ahb[m][k]*W[o][128+k] + b1[o]+b2[o]
// Block = 4 waves = 64 rows; wave = 16 rows x 128 cols; K=256 in 8 steps.
// ---------------------------------------------------------------------------
__global__ __launch_bounds__(256) void gemm_mfma(
    const float* __restrict__ feat, const ushort* __restrict__ ahb,
    const ushort* __restrict__ W, const float* __restrict__ b1,
    const float* __restrict__ b2, float* __restrict__ out, int ndst) {
  int wid = threadIdx.x >> 6;
  int lane = threadIdx.x & 63;
  int row0 = blockIdx.x * 64 + wid * 16;
  int r = lane & 15;
  int kg = lane >> 4;
  int arow = row0 + r;
  if (arow >= ndst) arow = ndst - 1;  // clamped lanes' results are discarded

  short8 afrag[8];
  const float* fr = feat + (size_t)arow * D;
  const ushort* ar = ahb + (size_t)arow * D;
#pragma unroll
  for (int s = 0; s < 4; ++s) {
    float4 lo = *(const float4*)(fr + s * 32 + kg * 8);
    float4 hi = *(const float4*)(fr + s * 32 + kg * 8 + 4);
    short8 t;
    t[0] = (short)f2bf(lo.x); t[1] = (short)f2bf(lo.y);
    t[2] = (short)f2bf(lo.z); t[3] = (short)f2bf(lo.w);
    t[4] = (short)f2bf(hi.x); t[5] = (short)f2bf(hi.y);
    t[6] = (short)f2bf(hi.z); t[7] = (short)f2bf(hi.w);
    afrag[s] = t;
    afrag[4 + s] = *(const short8*)(ar + s * 32 + kg * 8);
  }

  f32x4 acc[8];
#pragma unroll
  for (int n = 0; n < 8; ++n) acc[n] = (f32x4){0.f, 0.f, 0.f, 0.f};

#pragma unroll
  for (int n = 0; n < 8; ++n) {
    const ushort* wr = W + (size_t)(n * 16 + r) * KK;
#pragma unroll
    for (int s = 0; s < 8; ++s) {
      short8 bfrag = *(const short8*)(wr + s * 32 + kg * 8);
      acc[n] = __builtin_amdgcn_mfma_f32_16x16x32_bf16(afrag[s], bfrag, acc[n], 0, 0, 0);
    }
  }

#pragma unroll
  for (int n = 0; n < 8; ++n) {
    int col = n * 16 + r;
    float bb = b1[col] + b2[col];
#pragma unroll
    for (int q = 0; q < 4; ++q) {
      int orow = row0 + kg * 4 + q;
      if (orow < ndst) out[(size_t)orow * D + col] = acc[n][q] + bb;
    }
  }
}

extern "C" void kernel_launch(void* const* d_in, const int* in_sizes, int n_in,
                              void* d_out, int out_size, void* d_ws, size_t ws_size,
                              hipStream_t stream) {
  const float* feat    = (const float*)d_in[0];
  const float* in_norm = (const float*)d_in[1];
  const float* w1      = (const float*)d_in[2];
  const float* b1      = (const float*)d_in[3];
  const float* w2      = (const float*)d_in[4];
  const float* b2      = (const float*)d_in[5];
  const int*   src     = (const int*)d_in[6];
  const int*   dst     = (const int*)d_in[7];
  float*       out     = (float*)d_out;

  int E    = in_sizes[6];
  int ndst = in_sizes[1];
  int featn = in_sizes[0];  // N_SRC * D

  // workspace layout (16B-aligned pieces)
  char* ws = (char*)d_ws;
  uint* featf8 = (uint*)ws;                                    // featn fp8
  size_t off = (size_t)featn;
  ushort* ahb = (ushort*)(ws + off);  off += (size_t)ndst * D * sizeof(ushort);
  ushort* W = (ushort*)(ws + off);    off += (size_t)D * KK * sizeof(ushort);
  ushort* csr = (ushort*)(ws + off);  off += (((size_t)E + 7) & ~7ull) * sizeof(ushort);
  int* offs = (int*)(ws + off);       off += (size_t)ndst * sizeof(int);
  int* cursor = (int*)(ws + off);     off += (size_t)ndst * sizeof(int);
  int* bsums = (int*)(ws + off);

  int total16 = featn / 16;                    // 16 floats per thread
  int nb = (ndst + 255) / 256;                 // scan blocks (98 <= 256)
  int cblocks = (total16 + 255) / 256;
  if (cblocks < nb) cblocks = nb;

  conv_all<<<cblocks, 256, 0, stream>>>(
      feat, featf8, total16, w1, w2, W, in_norm, offs, bsums, ndst);
  finalize_offs<<<nb, 256, 0, stream>>>(offs, bsums, cursor, ndst, nb);
  int nj = (E + CH - 1) / CH;
  scatterx<<<8 * nj, 256, 0, stream>>>(src, dst, cursor, csr, E, ndst);
  gather_rows<<<(ndst + 3) / 4, 256, 0, stream>>>(
      featf8, csr, offs, cursor, in_norm, ahb, ndst);
  gemm_mfma<<<(ndst + 63) / 64, 256, 0, stream>>>(
      feat, ahb, W, b1, b2, out, ndst);
}